// Round 1
// baseline (384.441 us; speedup 1.0000x reference)
//
#include <hip/hip_runtime.h>
#include <hip/hip_bf16.h>
#include <cstdint>

// ---------------- problem dims ----------------
#define BS 8
#define SEQ 2048
#define HDIM 1024
#define NH 16
#define HD 64
#define M_ROWS (BS * SEQ)   // 16384
#define N_COLS (2 * HDIM)   // 2048 GEMM cols: 0..1023 = K1 (dots only), 1024..2047 = V1
#define KDIM HDIM           // 1024

#define DELTA 0.025f
#define FLAG_CAP 32768           // flat flagged-task list; expected ~6200 total

// ---------------- workspace layout (bytes) ----------------
#define OFF_A      ((size_t)0)           // bf16 A [M,K]             33,554,432
#define OFF_BT     ((size_t)33554432)    // bf16 Bt [N,K]             4,194,304
#define OFF_FCNT   ((size_t)37748736)    // int
#define OFF_FLIST  ((size_t)37748800)    // int[FLAG_CAP]               131,072
#define OFF_BIAS   ((size_t)37879872)    // f32 [2048]
#define OFF_CVH    ((size_t)41943040)    // bf16 CV [B][NH][SEQ][HD]  33,554,432
#define OFF_VALID  ((size_t)75497472)    // u8 [BS][NH][SEQ]             262,144
#define OFF_MAPS   ((size_t)75759616)    // ushort4 [BS][SEQ][NH]      2,097,152
// total ~78 MB

typedef __attribute__((ext_vector_type(8))) __bf16 bf16x8;
typedef __attribute__((ext_vector_type(4))) float f32x4;

// float -> bf16 bits, round-to-nearest-even (inputs are finite)
__device__ __forceinline__ unsigned short f2bf(float f) {
    unsigned int x = __builtin_bit_cast(unsigned int, f);
    unsigned int r = x + 0x7fffu + ((x >> 16) & 1u);
    return (unsigned short)(r >> 16);
}
__device__ __forceinline__ float bf2f(unsigned short u) {
    return __builtin_bit_cast(float, (unsigned int)u << 16);
}

// async 16B global -> LDS (dest = wave-uniform LDS base + lane*16)
__device__ __forceinline__ void g2l16(const void* gp, void* lp) {
    __builtin_amdgcn_global_load_lds(
        (__attribute__((address_space(1))) void*)(void*)gp,
        (__attribute__((address_space(3))) void*)lp, 16, 0, 0);
}

// ---------------- fused prep: hs->bf16 | W transpose->bf16 | bias+fcnt ----------------
__global__ __launch_bounds__(256) void prep_kernel(const float4* __restrict__ hs4,
                                                   ushort4* __restrict__ Abf4,
                                                   const float* __restrict__ K1w,
                                                   const float* __restrict__ V1w,
                                                   unsigned short* __restrict__ Bt,
                                                   const float* __restrict__ K1b,
                                                   const float* __restrict__ V1b,
                                                   float* __restrict__ bias,
                                                   int* __restrict__ fcnt) {
    __shared__ float tile[32][33];
    const int blk = blockIdx.x;
    const int t = threadIdx.x;
    if (blk < 16384) {
        int i = blk * 256 + t;            // 4,194,304 float4s
        float4 v = hs4[i];
        ushort4 o;
        o.x = f2bf(v.x); o.y = f2bf(v.y); o.z = f2bf(v.z); o.w = f2bf(v.w);
        Abf4[i] = o;
    } else if (blk < 18432) {
        int lb = blk - 16384;             // 0..2047 = tn + 32*tk + 1024*z
        int z = lb >> 10;
        int tk = (lb >> 5) & 31;
        int tn = lb & 31;
        const float* W = z ? V1w : K1w;
        int r = t >> 3;                   // 0..31
        int c4 = (t & 7) * 4;             // 0,4,..,28
        const float4 v = *(const float4*)&W[(size_t)(tk * 32 + r) * 1024 + tn * 32 + c4];
        tile[r][c4 + 0] = v.x; tile[r][c4 + 1] = v.y;
        tile[r][c4 + 2] = v.z; tile[r][c4 + 3] = v.w;
        __syncthreads();
        int n = tn * 32 + r;
        int k = tk * 32 + c4;
        ushort4 o;
        o.x = f2bf(tile[c4 + 0][r]); o.y = f2bf(tile[c4 + 1][r]);
        o.z = f2bf(tile[c4 + 2][r]); o.w = f2bf(tile[c4 + 3][r]);
        *(ushort4*)&Bt[((size_t)z * 1024 + n) * 1024 + k] = o;
    } else {
        int i = (blk - 18432) * 256 + t;  // 0..2047
        bias[i] = (i < 1024) ? K1b[i] : V1b[i - 1024];
        if (i == 0) *fcnt = 0;
    }
}

// ---------------- GEMM + fused dots ----------------
// 256x256 tile, BK=64, 8 waves (2M x 4N), per-wave 128x64 output, acc[8][4].
// Double-buffered LDS (2 x (As 32KB + Bs 32KB) = 128KB, 1 block/CU) with
// T3-minimum 2-phase pipeline: STAGE(next tile) issued BEFORE compute(cur);
// the single __syncthreads() per K-tile (emits s_waitcnt vmcnt(0) lgkmcnt(0)
// + s_barrier) lands the prefetch AFTER compute has covered its latency.
// Halves LDS-staged traffic per FLOP vs 128^2 (0.54 GB vs 1.07 GB/dispatch).
// XOR-swizzled staging (physical 16B-group g of row r holds logical g^(r&7)),
// identical to the verified 128^2 scheme: 0 bank conflicts measured.
// XCD-aware bijective swizzle (512 wgs % 8 == 0): each XCD gets a contiguous
// band of 8 M-panels x all 8 N-tiles -> A-panel re-reads become L2-local.
// n0 <  1024: fused dots epilogue (valid + flag list), K-half never stored.
// n0 >= 1024: relu(acc+bias) -> CVh bf16, HEAD-MAJOR layout [b][head][l][hd]
//             so gather's nearest-valid rows are adjacent 128B lines.
__global__ __launch_bounds__(512, 2) void gemm_kernel(const unsigned short* __restrict__ Abf,
                                                      const unsigned short* __restrict__ Btbf,
                                                      const float* __restrict__ bias,
                                                      const float* __restrict__ RH,
                                                      unsigned short* __restrict__ CVh,
                                                      unsigned char* __restrict__ valid,
                                                      int* __restrict__ fcnt,
                                                      int* __restrict__ flist) {
    constexpr int K = KDIM, BK = 64;
    __shared__ unsigned short As[2][256 * BK];   // 2 x 32KB
    __shared__ unsigned short Bs[2][256 * BK];   // 2 x 32KB
    const int t = threadIdx.x;                   // 0..511
    const int wave = t >> 6, lane = t & 63;
    const int wm = wave >> 2, wn = wave & 3;     // 2M x 4N wave grid
    const int l16 = lane & 15, quad = lane >> 4;
    const int sw = l16 & 7;                      // read-side XOR key (row&7 == l16&7)

    // XCD swizzle: hw assigns consecutive wgid round-robin across 8 XCDs;
    // remap so XCD k owns swz in [64k,64k+64) = M-band k*8..k*8+7, x-fastest.
    const int wgid = blockIdx.y * 8 + blockIdx.x;          // 0..511
    const int swz = (wgid & 7) * 64 + (wgid >> 3);
    const int m0 = (swz >> 3) * 256, n0 = (swz & 7) * 256;

    f32x4 zero4 = {0.f, 0.f, 0.f, 0.f};
    f32x4 acc[8][4];
#pragma unroll
    for (int i = 0; i < 8; i++)
#pragma unroll
        for (int j = 0; j < 4; j++) acc[i][j] = zero4;

    // staging roles: rr = row 0..63 (per issue), gsw = group ^ (row&7)
    const int rr = t >> 3;
    const int gsw = (t ^ rr) & 7;
    const unsigned short* gA = Abf + (size_t)(m0 + rr) * K + gsw * 8;
    const unsigned short* gB = Btbf + (size_t)(n0 + rr) * K + gsw * 8;
    char* lA = (char*)As + (size_t)wave * 1024;  // + buf*32768 + i*8192 (+lane*16 by HW)
    char* lB = (char*)Bs + (size_t)wave * 1024;

    auto stage = [&](int buf, int k0) {
        char* a = lA + buf * 32768;
        char* b = lB + buf * 32768;
#pragma unroll
        for (int i = 0; i < 4; i++) g2l16(gA + (size_t)i * 64 * K + k0, a + i * 8192);
#pragma unroll
        for (int i = 0; i < 4; i++) g2l16(gB + (size_t)i * 64 * K + k0, b + i * 8192);
    };

    auto compute = [&](int buf) {
        const unsigned short* Ab = As[buf];
        const unsigned short* Bb = Bs[buf];
#pragma unroll
        for (int h = 0; h < 2; h++) {
            const int hq = h * 4 + quad;
            bf16x8 af[8], bfr[4];
#pragma unroll
            for (int mt = 0; mt < 8; mt++)
                af[mt] = *(const bf16x8*)&Ab[(wm * 128 + mt * 16 + l16) * BK + ((hq ^ sw) << 3)];
#pragma unroll
            for (int nt = 0; nt < 4; nt++)
                bfr[nt] = *(const bf16x8*)&Bb[(wn * 64 + nt * 16 + l16) * BK + ((hq ^ sw) << 3)];
#pragma unroll
            for (int mt = 0; mt < 8; mt++)
#pragma unroll
                for (int nt = 0; nt < 4; nt++)
                    acc[mt][nt] = __builtin_amdgcn_mfma_f32_16x16x32_bf16(af[mt], bfr[nt], acc[mt][nt], 0, 0, 0);
        }
    };

    // 16 K-tiles; pair-unrolled so buffer index is compile-time.
    stage(0, 0);
    __syncthreads();
#pragma unroll 1
    for (int k0 = 64; k0 < 960; k0 += 128) {       // 7 iterations: tiles 1..14 staged
        stage(1, k0);      compute(0); __syncthreads();
        stage(0, k0 + 64); compute(1); __syncthreads();
    }
    stage(1, 960); compute(0); __syncthreads();
    compute(1);

    // C/D fragment: row = quad*4 + reg, col = l16 (within each 16x16 tile)
    if (n0 < HDIM) {
        // ---- fused dots: this wave's head ----
        const int n = (n0 >> 6) + wn;              // head 0..15
        float rh[4], bv[4];
#pragma unroll
        for (int nt = 0; nt < 4; nt++) {
            int col = n * 64 + nt * 16 + l16;
            rh[nt] = RH[col];
            bv[nt] = bias[col];
        }
#pragma unroll
        for (int mt = 0; mt < 8; mt++) {
#pragma unroll
            for (int r = 0; r < 4; r++) {
                float p = 0.f;
#pragma unroll
                for (int nt = 0; nt < 4; nt++)
                    p += fmaxf(acc[mt][nt][r] + bv[nt], 0.f) * rh[nt];
#pragma unroll
                for (int s = 8; s >= 1; s >>= 1) p += __shfl_xor(p, s, 64);
                if (l16 == 0) {
                    int row = m0 + wm * 128 + mt * 16 + quad * 4 + r;   // b*SEQ + l
                    int b = row >> 11, l = row & (SEQ - 1);
                    valid[((size_t)b * NH + n) * SEQ + l] = (p > 0.5f) ? 1 : 0;
                    if (fabsf(p - 0.5f) < DELTA) {
                        int idx = atomicAdd(fcnt, 1);
                        if (idx < FLAG_CAP) flist[idx] = row * NH + n;
                    }
                }
            }
        }
    } else {
        // ---- V-half: bias + relu, store bf16 to CVh [b][head][l][hd] ----
        const int nv0 = n0 - HDIM;
        const int head = (nv0 >> 6) + wn;          // 0..15 (wave-constant)
        const int b = m0 >> 11;                    // block-constant (256 | 2048)
        const int l0 = (m0 & (SEQ - 1)) + wm * 128 + quad * 4;
        unsigned short* plane = CVh + ((size_t)(b * NH + head)) * SEQ * HD;
#pragma unroll
        for (int mt = 0; mt < 8; mt++) {
#pragma unroll
            for (int nt = 0; nt < 4; nt++) {
                const int hd = nt * 16 + l16;
                const float bvv = bias[HDIM + nv0 + wn * 64 + hd];
#pragma unroll
                for (int r = 0; r < 4; r++)
                    plane[(size_t)(l0 + mt * 16 + r) * HD + hd] = f2bf(fmaxf(acc[mt][nt][r] + bvv, 0.f));
            }
        }
    }
}

// ---------------- exact fp64 refinement (R6 structure — works) ----------------
// Flat task list; 4 waves/block, ONE task per wave. Intra-iteration latency
// hiding: 32 independent weight dwords + 8 uniform float4 x's per k-group,
// one waitcnt, then 32 v_fma_f64.
__global__ __launch_bounds__(256) void refine_kernel(const float* __restrict__ hs,
                                                     const float* __restrict__ K1w,
                                                     const float* __restrict__ K1b,
                                                     const float* __restrict__ RH,
                                                     const int* __restrict__ fcnt,
                                                     const int* __restrict__ flist,
                                                     unsigned char* __restrict__ valid) {
    int cnt = *fcnt;
    if (cnt > FLAG_CAP) cnt = FLAG_CAP;
    const int wave = threadIdx.x >> 6, d = threadIdx.x & 63;
    const int task = blockIdx.x * 4 + wave;
    if (task >= cnt) return;

    const int code = flist[task];
    const int n = code & (NH - 1);
    const int bl = code >> 4;               // b*SEQ + l
    const float* x = hs + (size_t)bl * HDIM;
    const float* wp = K1w + n * 64 + d;     // stride 1024 over k, lane-coalesced

    double acc0 = 0.0, acc1 = 0.0, acc2 = 0.0, acc3 = 0.0;
    for (int k = 0; k < KDIM; k += 32) {
        float w[32];
#pragma unroll
        for (int u = 0; u < 32; u++)
            w[u] = wp[(size_t)(k + u) * 1024];
        float4 xv[8];
#pragma unroll
        for (int u = 0; u < 8; u++)
            xv[u] = *(const float4*)(x + k + u * 4);
#pragma unroll
        for (int u = 0; u < 8; u++) {
            acc0 += (double)xv[u].x * (double)w[u * 4 + 0];
            acc1 += (double)xv[u].y * (double)w[u * 4 + 1];
            acc2 += (double)xv[u].z * (double)w[u * 4 + 2];
            acc3 += (double)xv[u].w * (double)w[u * 4 + 3];
        }
    }
    double k1 = ((acc0 + acc1) + (acc2 + acc3)) + (double)K1b[n * 64 + d];
    if (k1 < 0.0) k1 = 0.0;
    double contrib = k1 * (double)RH[n * 64 + d];
#pragma unroll
    for (int s = 32; s >= 1; s >>= 1) contrib += __shfl_xor(contrib, s, 64);
    if (d == 0) {
        int b = bl >> 11, l = bl & (SEQ - 1);
        valid[((size_t)b * NH + n) * SEQ + l] = (contrib > 0.5) ? 1 : 0;
    }
}

// ---------------- nearest-valid scans ----------------
// one block (64 threads) per (b,n). Lane i owns positions [32i, 32i+32).
__global__ __launch_bounds__(64) void scan_kernel(const unsigned char* __restrict__ valid,
                                                  ushort4* __restrict__ maps) {
    int bn = blockIdx.x;                 // b*NH + n
    int b = bn >> 4, n = bn & (NH - 1);
    int lane = threadIdx.x;
    __shared__ unsigned int summ[64];

    const unsigned char* vp = valid + (size_t)bn * SEQ + lane * 32;
    uint4 c0 = *(const uint4*)vp;
    uint4 c1 = *(const uint4*)(vp + 16);
    unsigned int wds[8] = {c0.x, c0.y, c0.z, c0.w, c1.x, c1.y, c1.z, c1.w};
    unsigned int mask = 0;
#pragma unroll
    for (int i = 0; i < 8; i++) {
#pragma unroll
        for (int j = 0; j < 4; j++)
            mask |= (((wds[i] >> (8 * j)) & 0xffu) ? 1u : 0u) << (i * 4 + j);
    }

    // ---- forward ----
    int cnt = 0, va = 0, vb = 0;
#pragma unroll
    for (int tt = 0; tt < 32; tt++) {
        if (mask & (1u << tt)) { vb = va; va = lane * 32 + tt; cnt++; }
    }
    summ[lane] = (unsigned)((cnt > 2 ? 2 : cnt) | (va << 2) | (vb << 13));
    __syncthreads();
    int a = 0, bb_ = 0;
    for (int tt = 0; tt < lane; tt++) {
        unsigned s = summ[tt];
        int c = s & 3, sva = (s >> 2) & 2047, svb = (s >> 13) & 2047;
        if (c >= 2) { a = sva; bb_ = svb; }
        else if (c == 1) { bb_ = a; a = sva; }
    }
    unsigned int fres[32];
#pragma unroll
    for (int tt = 0; tt < 32; tt++) {
        if (mask & (1u << tt)) { bb_ = a; a = lane * 32 + tt; }
        fres[tt] = (unsigned)a | ((unsigned)bb_ << 16);
    }
    __syncthreads();

    // ---- backward (mirrored values) ----
    unsigned int maskb = mask;
    if (lane == 63) maskb &= ~(1u << 31);   // exclude j = L-1
    cnt = 0; va = 0; vb = 0;
#pragma unroll
    for (int tt = 31; tt >= 0; tt--) {
        if (maskb & (1u << tt)) { vb = va; va = (SEQ - 1) - (lane * 32 + tt); cnt++; }
    }
    summ[lane] = (unsigned)((cnt > 2 ? 2 : cnt) | (va << 2) | (vb << 13));
    __syncthreads();
    int a2 = SEQ - 1, b2 = SEQ - 1;
    for (int tt = 63; tt > lane; tt--) {
        unsigned s = summ[tt];
        int c = s & 3, sva = (s >> 2) & 2047, svb = (s >> 13) & 2047;
        if (c >= 2) { a2 = sva; b2 = svb; }
        else if (c == 1) { b2 = a2; a2 = sva; }
    }
#pragma unroll
    for (int tt = 31; tt >= 0; tt--) {
        int j = lane * 32 + tt;
        if (maskb & (1u << tt)) { b2 = a2; a2 = (SEQ - 1) - j; }
        unsigned f = fres[tt];
        maps[((size_t)b * SEQ + j) * NH + n] =
            make_ushort4((unsigned short)(f & 0xffffu), (unsigned short)(f >> 16),
                         (unsigned short)a2, (unsigned short)b2);
    }
}

// ---------------- gather + weighted sum (CVh bf16 [b][head][l][hd]) ----------------
// head-major planes: the 4 nearest-valid rows per (b,l,n) are 128B lines at
// stride 128B in l -> L2/L3-local since maps cluster near l.
__global__ __launch_bounds__(256) void gather_kernel(const unsigned short* __restrict__ CVh,
                                                     const ushort4* __restrict__ maps,
                                                     const float* __restrict__ bw,
                                                     float* __restrict__ out) {
    int bl = blockIdx.x;
    int t = threadIdx.x, n = t >> 4, q = t & 15;
    int b = bl >> 11;
    ushort4 m = maps[(size_t)bl * NH + n];
    const float4 w = *(const float4*)&bw[n * 4];
    const unsigned short* plane = CVh + ((size_t)(b * NH + n)) * SEQ * HD + q * 4;
    const ushort4 u0 = *(const ushort4*)&plane[(size_t)m.x * HD];
    const ushort4 u1 = *(const ushort4*)&plane[(size_t)m.y * HD];
    const ushort4 u2 = *(const ushort4*)&plane[(size_t)m.z * HD];
    const ushort4 u3 = *(const ushort4*)&plane[(size_t)m.w * HD];
    float4 o;
    o.x = w.x * bf2f(u0.x) + w.y * bf2f(u1.x) + w.z * bf2f(u2.x) + w.w * bf2f(u3.x);
    o.y = w.x * bf2f(u0.y) + w.y * bf2f(u1.y) + w.z * bf2f(u2.y) + w.w * bf2f(u3.y);
    o.z = w.x * bf2f(u0.z) + w.y * bf2f(u1.z) + w.z * bf2f(u2.z) + w.w * bf2f(u3.z);
    o.w = w.x * bf2f(u0.w) + w.y * bf2f(u1.w) + w.z * bf2f(u2.w) + w.w * bf2f(u3.w);
    *(float4*)&out[(size_t)bl * (NH * HD) + n * 64 + q * 4] = o;
}

// ---------------- launch ----------------
extern "C" void kernel_launch(void* const* d_in, const int* in_sizes, int n_in,
                              void* d_out, int out_size, void* d_ws, size_t ws_size,
                              hipStream_t stream) {
    (void)in_sizes; (void)n_in; (void)out_size; (void)ws_size;
    const float* hs  = (const float*)d_in[0];
    const float* K1w = (const float*)d_in[1];
    const float* K1b = (const float*)d_in[2];
    const float* V1w = (const float*)d_in[3];
    const float* V1b = (const float*)d_in[4];
    const float* bw  = (const float*)d_in[5];
    const float* RH  = (const float*)d_in[6];
    float* out = (float*)d_out;
    char* ws = (char*)d_ws;

    unsigned short* Abf  = (unsigned short*)(ws + OFF_A);
    unsigned short* Btbf = (unsigned short*)(ws + OFF_BT);
    int* fcnt = (int*)(ws + OFF_FCNT);
    int* flist = (int*)(ws + OFF_FLIST);
    float* bias  = (float*)(ws + OFF_BIAS);
    unsigned short* CVh = (unsigned short*)(ws + OFF_CVH);
    unsigned char* valid = (unsigned char*)(ws + OFF_VALID);
    ushort4* maps = (ushort4*)(ws + OFF_MAPS);

    prep_kernel<<<18440, 256, 0, stream>>>((const float4*)hs, (ushort4*)Abf,
                                           K1w, V1w, Btbf, K1b, V1b, bias, fcnt);
    gemm_kernel<<<dim3(N_COLS / 256, M_ROWS / 256), 512, 0, stream>>>(
        Abf, Btbf, bias, RH, CVh, valid, fcnt, flist);
    refine_kernel<<<FLAG_CAP / 4, 256, 0, stream>>>(
        hs, K1w, K1b, RH, fcnt, flist, valid);
    scan_kernel<<<BS * NH, 64, 0, stream>>>(valid, maps);
    gather_kernel<<<BS * SEQ, 256, 0, stream>>>(CVh, maps, bw, out);
}

// Round 2
// 383.487 us; speedup vs baseline: 1.0025x; 1.0025x over previous
//
#include <hip/hip_runtime.h>
#include <hip/hip_bf16.h>
#include <cstdint>

// ---------------- problem dims ----------------
#define BS 8
#define SEQ 2048
#define HDIM 1024
#define NH 16
#define HD 64
#define M_ROWS (BS * SEQ)   // 16384
#define N_COLS (2 * HDIM)   // 2048 GEMM cols: 0..1023 = K1 (dots only), 1024..2047 = V1
#define KDIM HDIM           // 1024

#define DELTA 0.025f
#define FLAG_CAP 32768           // flat flagged-task list; expected ~6200 total

// ---------------- workspace layout (bytes) ----------------
#define OFF_A      ((size_t)0)           // bf16 A [M,K]             33,554,432
#define OFF_BT     ((size_t)33554432)    // bf16 Bt [N,K]             4,194,304
#define OFF_FCNT   ((size_t)37748736)    // int
#define OFF_FLIST  ((size_t)37748800)    // int[FLAG_CAP]               131,072
#define OFF_BIAS   ((size_t)37879872)    // f32 [2048]
#define OFF_CVH    ((size_t)41943040)    // bf16 CV [B][NH][SEQ][HD]  33,554,432
#define OFF_VALID  ((size_t)75497472)    // u8 [BS][NH][SEQ]             262,144
#define OFF_MAPS   ((size_t)75759616)    // ushort4 [BS][SEQ][NH]      2,097,152
// total ~78 MB

typedef __attribute__((ext_vector_type(8))) __bf16 bf16x8;
typedef __attribute__((ext_vector_type(4))) float f32x4;

// float -> bf16 bits, round-to-nearest-even (inputs are finite)
__device__ __forceinline__ unsigned short f2bf(float f) {
    unsigned int x = __builtin_bit_cast(unsigned int, f);
    unsigned int r = x + 0x7fffu + ((x >> 16) & 1u);
    return (unsigned short)(r >> 16);
}
__device__ __forceinline__ float bf2f(unsigned short u) {
    return __builtin_bit_cast(float, (unsigned int)u << 16);
}

// async 16B global -> LDS (dest = wave-uniform LDS base + lane*16)
__device__ __forceinline__ void g2l16(const void* gp, void* lp) {
    __builtin_amdgcn_global_load_lds(
        (__attribute__((address_space(1))) void*)(void*)gp,
        (__attribute__((address_space(3))) void*)lp, 16, 0, 0);
}

// ---------------- fused prep: hs->bf16 | W transpose->bf16 | bias+fcnt ----------------
__global__ __launch_bounds__(256) void prep_kernel(const float4* __restrict__ hs4,
                                                   ushort4* __restrict__ Abf4,
                                                   const float* __restrict__ K1w,
                                                   const float* __restrict__ V1w,
                                                   unsigned short* __restrict__ Bt,
                                                   const float* __restrict__ K1b,
                                                   const float* __restrict__ V1b,
                                                   float* __restrict__ bias,
                                                   int* __restrict__ fcnt) {
    __shared__ float tile[32][33];
    const int blk = blockIdx.x;
    const int t = threadIdx.x;
    if (blk < 16384) {
        int i = blk * 256 + t;            // 4,194,304 float4s
        float4 v = hs4[i];
        ushort4 o;
        o.x = f2bf(v.x); o.y = f2bf(v.y); o.z = f2bf(v.z); o.w = f2bf(v.w);
        Abf4[i] = o;
    } else if (blk < 18432) {
        int lb = blk - 16384;             // 0..2047 = tn + 32*tk + 1024*z
        int z = lb >> 10;
        int tk = (lb >> 5) & 31;
        int tn = lb & 31;
        const float* W = z ? V1w : K1w;
        int r = t >> 3;                   // 0..31
        int c4 = (t & 7) * 4;             // 0,4,..,28
        const float4 v = *(const float4*)&W[(size_t)(tk * 32 + r) * 1024 + tn * 32 + c4];
        tile[r][c4 + 0] = v.x; tile[r][c4 + 1] = v.y;
        tile[r][c4 + 2] = v.z; tile[r][c4 + 3] = v.w;
        __syncthreads();
        int n = tn * 32 + r;
        int k = tk * 32 + c4;
        ushort4 o;
        o.x = f2bf(tile[c4 + 0][r]); o.y = f2bf(tile[c4 + 1][r]);
        o.z = f2bf(tile[c4 + 2][r]); o.w = f2bf(tile[c4 + 3][r]);
        *(ushort4*)&Bt[((size_t)z * 1024 + n) * 1024 + k] = o;
    } else {
        int i = (blk - 18432) * 256 + t;  // 0..2047
        bias[i] = (i < 1024) ? K1b[i] : V1b[i - 1024];
        if (i == 0) *fcnt = 0;
    }
}

// ---------------- GEMM + fused dots ----------------
// 256x256 tile, BK=64, 8 waves (2M x 4N), per-wave 128x64 output, acc[8][4].
// T3+T4 schedule: 4 phases per K-tile. Each phase issues 2 chunk-DMAs
// (global_load_lds, 8KB each) for tile t+1, then s_waitcnt vmcnt(4) + raw
// s_barrier, then one quadrant (mh,kk) of 16 MFMA. vmcnt is NEVER drained
// to 0 in the loop: vmcnt(4) allows the last 2 phases' chunks in flight
// while guaranteeing chunks staged >=3 phase-slots ago have landed.
// Stage order per tile: [B0,B1][B2,B3][A0,A2][A1,A3]; consume order:
// ph1 (mh0,kk0) needs B*+A{0,2}; ph2 (mh1,kk0) needs A{1,3}; ph3/ph4 reuse.
// Ledger verified: at each phase's wait, the needed chunks are always older
// than the newest 4 outstanding. Overwrite safety: every stage into buf X
// is >=1 barrier after X's last ds_read (tile-end barrier). Tail keeps the
// ledger uniform by re-staging k=960. Trailing vmcnt(0) before epilogue
// (DMA must not land after LDS dealloc).
// XOR-swizzled staging (physical 16B-group g of row r holds logical g^(r&7));
// XCD-aware bijective swizzle (512 wgs % 8 == 0).
// n0 <  1024: fused dots epilogue (valid + flag list), K-half never stored.
// n0 >= 1024: relu(acc+bias) -> CVh bf16, HEAD-MAJOR layout [b][head][l][hd].
__global__ __launch_bounds__(512, 2) void gemm_kernel(const unsigned short* __restrict__ Abf,
                                                      const unsigned short* __restrict__ Btbf,
                                                      const float* __restrict__ bias,
                                                      const float* __restrict__ RH,
                                                      unsigned short* __restrict__ CVh,
                                                      unsigned char* __restrict__ valid,
                                                      int* __restrict__ fcnt,
                                                      int* __restrict__ flist) {
    constexpr int K = KDIM;
    __shared__ unsigned short As[2][256 * 64];   // 2 x 32KB
    __shared__ unsigned short Bs[2][256 * 64];   // 2 x 32KB
    const int t = threadIdx.x;                   // 0..511
    const int wave = t >> 6, lane = t & 63;
    const int wm = wave >> 2, wn = wave & 3;     // 2M x 4N wave grid
    const int l16 = lane & 15, quad = lane >> 4;
    const int sw = l16 & 7;                      // read-side XOR key (row&7 == l16&7)

    const int wgid = blockIdx.y * 8 + blockIdx.x;          // 0..511
    const int swz = (wgid & 7) * 64 + (wgid >> 3);
    const int m0 = (swz >> 3) * 256, n0 = (swz & 7) * 256;

    f32x4 zero4 = {0.f, 0.f, 0.f, 0.f};
    f32x4 acc[8][4];
#pragma unroll
    for (int i = 0; i < 8; i++)
#pragma unroll
        for (int j = 0; j < 4; j++) acc[i][j] = zero4;

    // staging roles: rr = row 0..63 (per chunk), gsw = group ^ (row&7)
    const int rr = t >> 3;
    const int gsw = (t ^ rr) & 7;
    const unsigned short* gA = Abf + (size_t)(m0 + rr) * K + gsw * 8;
    const unsigned short* gB = Btbf + (size_t)(n0 + rr) * K + gsw * 8;
    char* lA = (char*)As + (size_t)wave * 1024;  // + buf*32768 + chunk*8192 (+lane*16 by HW)
    char* lB = (char*)Bs + (size_t)wave * 1024;

    // one 8KB chunk = 64 rows x 64 cols bf16; 1 DMA instr per wave per chunk
    auto stA = [&](int buf, int i, int kn) {
        g2l16(gA + (size_t)i * 64 * K + kn, lA + buf * 32768 + i * 8192);
    };
    auto stB = [&](int buf, int i, int kn) {
        g2l16(gB + (size_t)i * 64 * K + kn, lB + buf * 32768 + i * 8192);
    };

    // one quadrant: 4 A-frags x 4 B-frags at k-slice kk4 (0 or 4), 16 MFMA
    auto quad4 = [&](int buf, int mh, int kk4) {
        const unsigned short* Ab = As[buf];
        const unsigned short* Bb = Bs[buf];
        const int g = (((kk4 + quad) ^ sw) << 3);
        bf16x8 af[4], bfr[4];
#pragma unroll
        for (int mt = 0; mt < 4; mt++)
            af[mt] = *(const bf16x8*)&Ab[(wm * 128 + mh * 64 + mt * 16 + l16) * 64 + g];
#pragma unroll
        for (int nt = 0; nt < 4; nt++)
            bfr[nt] = *(const bf16x8*)&Bb[(wn * 64 + nt * 16 + l16) * 64 + g];
        __builtin_amdgcn_s_setprio(1);
#pragma unroll
        for (int mt = 0; mt < 4; mt++)
#pragma unroll
            for (int nt = 0; nt < 4; nt++)
                acc[mh * 4 + mt][nt] =
                    __builtin_amdgcn_mfma_f32_16x16x32_bf16(af[mt], bfr[nt], acc[mh * 4 + mt][nt], 0, 0, 0);
        __builtin_amdgcn_s_setprio(0);
    };

#define VW4 asm volatile("s_waitcnt vmcnt(4)" ::: "memory")
#define BARR __builtin_amdgcn_s_barrier()

    // prologue: tile 0 -> buf0, canonical order B0..B3, A0, A2, A1, A3
    stB(0, 0, 0); stB(0, 1, 0); stB(0, 2, 0); stB(0, 3, 0);
    stA(0, 0, 0); stA(0, 2, 0); stA(0, 1, 0); stA(0, 3, 0);

#pragma unroll 1
    for (int tp = 0; tp < 8; ++tp) {
        const int ka = tp * 128 + 64;                       // tile 2tp+1 (<= 960)
        const int kb = (tp == 7) ? 960 : tp * 128 + 128;    // tile 2tp+2 (tail restage)
        // ---- tile 2tp from buf0; stage tile 2tp+1 -> buf1 ----
        stB(1, 0, ka); stB(1, 1, ka); VW4; BARR; quad4(0, 0, 0);
        stB(1, 2, ka); stB(1, 3, ka); VW4; BARR; quad4(0, 1, 0);
        stA(1, 0, ka); stA(1, 2, ka); VW4; BARR; quad4(0, 0, 4);
        stA(1, 1, ka); stA(1, 3, ka); VW4; BARR; quad4(0, 1, 4);
        BARR;   // tile-end: buf0 reads done before next stages target buf0
        // ---- tile 2tp+1 from buf1; stage tile 2tp+2 -> buf0 ----
        stB(0, 0, kb); stB(0, 1, kb); VW4; BARR; quad4(1, 0, 0);
        stB(0, 2, kb); stB(0, 3, kb); VW4; BARR; quad4(1, 1, 0);
        stA(0, 0, kb); stA(0, 2, kb); VW4; BARR; quad4(1, 0, 4);
        stA(0, 1, kb); stA(0, 3, kb); VW4; BARR; quad4(1, 1, 4);
        BARR;   // tile-end: buf1 reads done before next stages target buf1
    }
    // drain: DMA must not land after LDS dealloc / epilogue
    asm volatile("s_waitcnt vmcnt(0)" ::: "memory");
#undef VW4
#undef BARR

    // C/D fragment: row = quad*4 + reg, col = l16 (within each 16x16 tile)
    if (n0 < HDIM) {
        // ---- fused dots: this wave's head ----
        const int n = (n0 >> 6) + wn;              // head 0..15
        float rh[4], bv[4];
#pragma unroll
        for (int nt = 0; nt < 4; nt++) {
            int col = n * 64 + nt * 16 + l16;
            rh[nt] = RH[col];
            bv[nt] = bias[col];
        }
#pragma unroll
        for (int mt = 0; mt < 8; mt++) {
#pragma unroll
            for (int r = 0; r < 4; r++) {
                float p = 0.f;
#pragma unroll
                for (int nt = 0; nt < 4; nt++)
                    p += fmaxf(acc[mt][nt][r] + bv[nt], 0.f) * rh[nt];
#pragma unroll
                for (int s = 8; s >= 1; s >>= 1) p += __shfl_xor(p, s, 64);
                if (l16 == 0) {
                    int row = m0 + wm * 128 + mt * 16 + quad * 4 + r;   // b*SEQ + l
                    int b = row >> 11, l = row & (SEQ - 1);
                    valid[((size_t)b * NH + n) * SEQ + l] = (p > 0.5f) ? 1 : 0;
                    if (fabsf(p - 0.5f) < DELTA) {
                        int idx = atomicAdd(fcnt, 1);
                        if (idx < FLAG_CAP) flist[idx] = row * NH + n;
                    }
                }
            }
        }
    } else {
        // ---- V-half: bias + relu, store bf16 to CVh [b][head][l][hd] ----
        const int nv0 = n0 - HDIM;
        const int head = (nv0 >> 6) + wn;          // 0..15 (wave-constant)
        const int b = m0 >> 11;                    // block-constant
        const int l0 = (m0 & (SEQ - 1)) + wm * 128 + quad * 4;
        unsigned short* plane = CVh + ((size_t)(b * NH + head)) * SEQ * HD;
#pragma unroll
        for (int mt = 0; mt < 8; mt++) {
#pragma unroll
            for (int nt = 0; nt < 4; nt++) {
                const int hd = nt * 16 + l16;
                const float bvv = bias[HDIM + nv0 + wn * 64 + hd];
#pragma unroll
                for (int r = 0; r < 4; r++)
                    plane[(size_t)(l0 + mt * 16 + r) * HD + hd] = f2bf(fmaxf(acc[mt][nt][r] + bvv, 0.f));
            }
        }
    }
}

// ---------------- exact fp64 refinement (R6 structure — works) ----------------
__global__ __launch_bounds__(256) void refine_kernel(const float* __restrict__ hs,
                                                     const float* __restrict__ K1w,
                                                     const float* __restrict__ K1b,
                                                     const float* __restrict__ RH,
                                                     const int* __restrict__ fcnt,
                                                     const int* __restrict__ flist,
                                                     unsigned char* __restrict__ valid) {
    int cnt = *fcnt;
    if (cnt > FLAG_CAP) cnt = FLAG_CAP;
    const int wave = threadIdx.x >> 6, d = threadIdx.x & 63;
    const int task = blockIdx.x * 4 + wave;
    if (task >= cnt) return;

    const int code = flist[task];
    const int n = code & (NH - 1);
    const int bl = code >> 4;               // b*SEQ + l
    const float* x = hs + (size_t)bl * HDIM;
    const float* wp = K1w + n * 64 + d;     // stride 1024 over k, lane-coalesced

    double acc0 = 0.0, acc1 = 0.0, acc2 = 0.0, acc3 = 0.0;
    for (int k = 0; k < KDIM; k += 32) {
        float w[32];
#pragma unroll
        for (int u = 0; u < 32; u++)
            w[u] = wp[(size_t)(k + u) * 1024];
        float4 xv[8];
#pragma unroll
        for (int u = 0; u < 8; u++)
            xv[u] = *(const float4*)(x + k + u * 4);
#pragma unroll
        for (int u = 0; u < 8; u++) {
            acc0 += (double)xv[u].x * (double)w[u * 4 + 0];
            acc1 += (double)xv[u].y * (double)w[u * 4 + 1];
            acc2 += (double)xv[u].z * (double)w[u * 4 + 2];
            acc3 += (double)xv[u].w * (double)w[u * 4 + 3];
        }
    }
    double k1 = ((acc0 + acc1) + (acc2 + acc3)) + (double)K1b[n * 64 + d];
    if (k1 < 0.0) k1 = 0.0;
    double contrib = k1 * (double)RH[n * 64 + d];
#pragma unroll
    for (int s = 32; s >= 1; s >>= 1) contrib += __shfl_xor(contrib, s, 64);
    if (d == 0) {
        int b = bl >> 11, l = bl & (SEQ - 1);
        valid[((size_t)b * NH + n) * SEQ + l] = (contrib > 0.5) ? 1 : 0;
    }
}

// ---------------- nearest-valid scans ----------------
__global__ __launch_bounds__(64) void scan_kernel(const unsigned char* __restrict__ valid,
                                                  ushort4* __restrict__ maps) {
    int bn = blockIdx.x;                 // b*NH + n
    int b = bn >> 4, n = bn & (NH - 1);
    int lane = threadIdx.x;
    __shared__ unsigned int summ[64];

    const unsigned char* vp = valid + (size_t)bn * SEQ + lane * 32;
    uint4 c0 = *(const uint4*)vp;
    uint4 c1 = *(const uint4*)(vp + 16);
    unsigned int wds[8] = {c0.x, c0.y, c0.z, c0.w, c1.x, c1.y, c1.z, c1.w};
    unsigned int mask = 0;
#pragma unroll
    for (int i = 0; i < 8; i++) {
#pragma unroll
        for (int j = 0; j < 4; j++)
            mask |= (((wds[i] >> (8 * j)) & 0xffu) ? 1u : 0u) << (i * 4 + j);
    }

    // ---- forward ----
    int cnt = 0, va = 0, vb = 0;
#pragma unroll
    for (int tt = 0; tt < 32; tt++) {
        if (mask & (1u << tt)) { vb = va; va = lane * 32 + tt; cnt++; }
    }
    summ[lane] = (unsigned)((cnt > 2 ? 2 : cnt) | (va << 2) | (vb << 13));
    __syncthreads();
    int a = 0, bb_ = 0;
    for (int tt = 0; tt < lane; tt++) {
        unsigned s = summ[tt];
        int c = s & 3, sva = (s >> 2) & 2047, svb = (s >> 13) & 2047;
        if (c >= 2) { a = sva; bb_ = svb; }
        else if (c == 1) { bb_ = a; a = sva; }
    }
    unsigned int fres[32];
#pragma unroll
    for (int tt = 0; tt < 32; tt++) {
        if (mask & (1u << tt)) { bb_ = a; a = lane * 32 + tt; }
        fres[tt] = (unsigned)a | ((unsigned)bb_ << 16);
    }
    __syncthreads();

    // ---- backward (mirrored values) ----
    unsigned int maskb = mask;
    if (lane == 63) maskb &= ~(1u << 31);   // exclude j = L-1
    cnt = 0; va = 0; vb = 0;
#pragma unroll
    for (int tt = 31; tt >= 0; tt--) {
        if (maskb & (1u << tt)) { vb = va; va = (SEQ - 1) - (lane * 32 + tt); cnt++; }
    }
    summ[lane] = (unsigned)((cnt > 2 ? 2 : cnt) | (va << 2) | (vb << 13));
    __syncthreads();
    int a2 = SEQ - 1, b2 = SEQ - 1;
    for (int tt = 63; tt > lane; tt--) {
        unsigned s = summ[tt];
        int c = s & 3, sva = (s >> 2) & 2047, svb = (s >> 13) & 2047;
        if (c >= 2) { a2 = sva; b2 = svb; }
        else if (c == 1) { b2 = a2; a2 = sva; }
    }
#pragma unroll
    for (int tt = 31; tt >= 0; tt--) {
        int j = lane * 32 + tt;
        if (maskb & (1u << tt)) { b2 = a2; a2 = (SEQ - 1) - j; }
        unsigned f = fres[tt];
        maps[((size_t)b * SEQ + j) * NH + n] =
            make_ushort4((unsigned short)(f & 0xffffu), (unsigned short)(f >> 16),
                         (unsigned short)a2, (unsigned short)b2);
    }
}

// ---------------- gather + weighted sum (CVh bf16 [b][head][l][hd]) ----------------
__global__ __launch_bounds__(256) void gather_kernel(const unsigned short* __restrict__ CVh,
                                                     const ushort4* __restrict__ maps,
                                                     const float* __restrict__ bw,
                                                     float* __restrict__ out) {
    int bl = blockIdx.x;
    int t = threadIdx.x, n = t >> 4, q = t & 15;
    int b = bl >> 11;
    ushort4 m = maps[(size_t)bl * NH + n];
    const float4 w = *(const float4*)&bw[n * 4];
    const unsigned short* plane = CVh + ((size_t)(b * NH + n)) * SEQ * HD + q * 4;
    const ushort4 u0 = *(const ushort4*)&plane[(size_t)m.x * HD];
    const ushort4 u1 = *(const ushort4*)&plane[(size_t)m.y * HD];
    const ushort4 u2 = *(const ushort4*)&plane[(size_t)m.z * HD];
    const ushort4 u3 = *(const ushort4*)&plane[(size_t)m.w * HD];
    float4 o;
    o.x = w.x * bf2f(u0.x) + w.y * bf2f(u1.x) + w.z * bf2f(u2.x) + w.w * bf2f(u3.x);
    o.y = w.x * bf2f(u0.y) + w.y * bf2f(u1.y) + w.z * bf2f(u2.y) + w.w * bf2f(u3.y);
    o.z = w.x * bf2f(u0.z) + w.y * bf2f(u1.z) + w.z * bf2f(u2.z) + w.w * bf2f(u3.z);
    o.w = w.x * bf2f(u0.w) + w.y * bf2f(u1.w) + w.z * bf2f(u2.w) + w.w * bf2f(u3.w);
    *(float4*)&out[(size_t)bl * (NH * HD) + n * 64 + q * 4] = o;
}

// ---------------- launch ----------------
extern "C" void kernel_launch(void* const* d_in, const int* in_sizes, int n_in,
                              void* d_out, int out_size, void* d_ws, size_t ws_size,
                              hipStream_t stream) {
    (void)in_sizes; (void)n_in; (void)out_size; (void)ws_size;
    const float* hs  = (const float*)d_in[0];
    const float* K1w = (const float*)d_in[1];
    const float* K1b = (const float*)d_in[2];
    const float* V1w = (const float*)d_in[3];
    const float* V1b = (const float*)d_in[4];
    const float* bw  = (const float*)d_in[5];
    const float* RH  = (const float*)d_in[6];
    float* out = (float*)d_out;
    char* ws = (char*)d_ws;

    unsigned short* Abf  = (unsigned short*)(ws + OFF_A);
    unsigned short* Btbf = (unsigned short*)(ws + OFF_BT);
    int* fcnt = (int*)(ws + OFF_FCNT);
    int* flist = (int*)(ws + OFF_FLIST);
    float* bias  = (float*)(ws + OFF_BIAS);
    unsigned short* CVh = (unsigned short*)(ws + OFF_CVH);
    unsigned char* valid = (unsigned char*)(ws + OFF_VALID);
    ushort4* maps = (ushort4*)(ws + OFF_MAPS);

    prep_kernel<<<18440, 256, 0, stream>>>((const float4*)hs, (ushort4*)Abf,
                                           K1w, V1w, Btbf, K1b, V1b, bias, fcnt);
    gemm_kernel<<<dim3(N_COLS / 256, M_ROWS / 256), 512, 0, stream>>>(
        Abf, Btbf, bias, RH, CVh, valid, fcnt, flist);
    refine_kernel<<<FLAG_CAP / 4, 256, 0, stream>>>(
        hs, K1w, K1b, RH, fcnt, flist, valid);
    scan_kernel<<<BS * NH, 64, 0, stream>>>(valid, maps);
    gather_kernel<<<BS * SEQ, 256, 0, stream>>>(CVh, maps, bw, out);
}